// Round 1
// baseline (748.377 us; speedup 1.0000x reference)
//
#include <hip/hip_runtime.h>
#include <math.h>

// Problem constants
constexpr int B_ = 8, S_ = 32, D_ = 256, M_ = 2048;
constexpr int N_ = S_ * B_;          // 256 (t,b) pairs, n = t*B + b
constexpr int TK = 8;                // TOPK
constexpr int NSLOT = 256;           // max distinct touched rows (8*32)
constexpr int TOPC = 256;            // precomputed top-C of L0 per (t,b)
constexpr int NCAND = NSLOT + TOPC;  // 512

// ---------------------------------------------------------------------------
// K0: WkT[j][i] = Wk[i][j]  (so qt = Wk @ q reads coalesced)
// ---------------------------------------------------------------------------
__global__ void k_transpose(const float* __restrict__ Wk, float* __restrict__ WkT) {
  __shared__ float tile[32][33];
  int bx = blockIdx.x & 7, by = blockIdx.x >> 3;
  int x0 = bx * 32, y0 = by * 32;
  int tx = threadIdx.x & 31, ty = threadIdx.x >> 5;  // 256 thr -> ty 0..7
  for (int j = ty; j < 32; j += 8) tile[j][tx] = Wk[(y0 + j) * D_ + x0 + tx];
  __syncthreads();
  for (int j = ty; j < 32; j += 8) WkT[(x0 + j) * D_ + y0 + tx] = tile[tx][j];
}

// ---------------------------------------------------------------------------
// K1: per n=(t,b): q = xt@Wq+bq ; qt = WkT^T ... i.e. qt[d]=sum_i q[i]*WkT[i][d]
//     qbk = q . bk ; xgpre = xt @ Wg[0:D,:]
// ---------------------------------------------------------------------------
__global__ __launch_bounds__(256) void k_qproj(
    const float* __restrict__ x, const float* __restrict__ Wq,
    const float* __restrict__ bq, const float* __restrict__ bk,
    const float* __restrict__ WkT, const float* __restrict__ Wg,
    float* __restrict__ qt, float* __restrict__ qbk, float* __restrict__ xgp) {
  int n = blockIdx.x, tid = threadIdx.x;
  int t = n / B_, b = n % B_;
  __shared__ float xr[D_], qsh[D_];
  __shared__ float red[4];
  xr[tid] = x[(b * S_ + t) * D_ + tid];
  __syncthreads();
  float accq = bq[tid], accg = 0.f;
  for (int i = 0; i < D_; ++i) {
    float xv = xr[i];
    accq = fmaf(xv, Wq[i * D_ + tid], accq);
    accg = fmaf(xv, Wg[i * D_ + tid], accg);
  }
  qsh[tid] = accq;
  xgp[n * D_ + tid] = accg;
  float p = accq * bk[tid];
  for (int off = 32; off > 0; off >>= 1) p += __shfl_down(p, off, 64);
  if ((tid & 63) == 0) red[tid >> 6] = p;
  __syncthreads();
  float acct = 0.f;
  for (int i = 0; i < D_; ++i) acct = fmaf(qsh[i], WkT[i * D_ + tid], acct);
  qt[n * D_ + tid] = acct;
  if (tid == 0) qbk[n] = red[0] + red[1] + red[2] + red[3];
}

// ---------------------------------------------------------------------------
// K2: L0[n][m] = (memory[m] . qt[n] + qbk[n]) / 16      GEMM 2048x256x256
// tiles 64(m) x 64(n), K chunked by 64, transposed-in-k LDS tiles, float4
// ---------------------------------------------------------------------------
__global__ __launch_bounds__(256) void k_L0(
    const float* __restrict__ qt, const float* __restrict__ mem,
    const float* __restrict__ qbk, float* __restrict__ L0) {
  __shared__ float qtT[64 * 64];
  __shared__ float mT[64 * 64];
  const int tid = threadIdx.x;
  const int m0 = blockIdx.x * 64, n0 = blockIdx.y * 64;
  const int r = tid & 63, c = tid >> 6;
  const int lane = tid & 63, wv = tid >> 6;
  const int tx = lane & 15, ty = lane >> 4;
  const int mg = tx * 4, ng = (wv * 4 + ty) * 4;
  float acc[4][4];
#pragma unroll
  for (int i = 0; i < 4; ++i)
#pragma unroll
    for (int j = 0; j < 4; ++j) acc[i][j] = 0.f;
  for (int kc = 0; kc < 4; ++kc) {
    __syncthreads();
#pragma unroll
    for (int it = 0; it < 4; ++it) {
      int kq = (c * 4 + it) * 4;
      float4 a = *(const float4*)&qt[(n0 + r) * D_ + kc * 64 + kq];
      qtT[(kq + 0) * 64 + r] = a.x; qtT[(kq + 1) * 64 + r] = a.y;
      qtT[(kq + 2) * 64 + r] = a.z; qtT[(kq + 3) * 64 + r] = a.w;
      float4 bm = *(const float4*)&mem[(m0 + r) * D_ + kc * 64 + kq];
      mT[(kq + 0) * 64 + r] = bm.x; mT[(kq + 1) * 64 + r] = bm.y;
      mT[(kq + 2) * 64 + r] = bm.z; mT[(kq + 3) * 64 + r] = bm.w;
    }
    __syncthreads();
#pragma unroll 4
    for (int k = 0; k < 64; ++k) {
      float4 av = *(const float4*)&qtT[k * 64 + ng];
      float4 bv4 = *(const float4*)&mT[k * 64 + mg];
      acc[0][0] = fmaf(av.x, bv4.x, acc[0][0]); acc[0][1] = fmaf(av.x, bv4.y, acc[0][1]);
      acc[0][2] = fmaf(av.x, bv4.z, acc[0][2]); acc[0][3] = fmaf(av.x, bv4.w, acc[0][3]);
      acc[1][0] = fmaf(av.y, bv4.x, acc[1][0]); acc[1][1] = fmaf(av.y, bv4.y, acc[1][1]);
      acc[1][2] = fmaf(av.y, bv4.z, acc[1][2]); acc[1][3] = fmaf(av.y, bv4.w, acc[1][3]);
      acc[2][0] = fmaf(av.z, bv4.x, acc[2][0]); acc[2][1] = fmaf(av.z, bv4.y, acc[2][1]);
      acc[2][2] = fmaf(av.z, bv4.z, acc[2][2]); acc[2][3] = fmaf(av.z, bv4.w, acc[2][3]);
      acc[3][0] = fmaf(av.w, bv4.x, acc[3][0]); acc[3][1] = fmaf(av.w, bv4.y, acc[3][1]);
      acc[3][2] = fmaf(av.w, bv4.z, acc[3][2]); acc[3][3] = fmaf(av.w, bv4.w, acc[3][3]);
    }
  }
#pragma unroll
  for (int i = 0; i < 4; ++i) {
    int n = n0 + ng + i;
    float qbv = qbk[n];
    float4 o;
    o.x = (acc[i][0] + qbv) * 0.0625f; o.y = (acc[i][1] + qbv) * 0.0625f;
    o.z = (acc[i][2] + qbv) * 0.0625f; o.w = (acc[i][3] + qbv) * 0.0625f;
    *(float4*)&L0[n * M_ + m0 + mg] = o;
  }
}

// ---------------------------------------------------------------------------
// K3a: per n: M0 = max_m L0 ; SumE0 = sum_m exp(L0-M0)  (fp64 accumulate)
// ---------------------------------------------------------------------------
__global__ __launch_bounds__(256) void k_stats(const float* __restrict__ L0,
                                               float* __restrict__ M0,
                                               double* __restrict__ SumE0) {
  int n = blockIdx.x, tid = threadIdx.x;
  __shared__ float redf[4];
  __shared__ double redd[4];
  __shared__ float mxs;
  float mx = -INFINITY;
  for (int m = tid; m < M_; m += 256) mx = fmaxf(mx, L0[n * M_ + m]);
  for (int off = 32; off > 0; off >>= 1) mx = fmaxf(mx, __shfl_down(mx, off, 64));
  if ((tid & 63) == 0) redf[tid >> 6] = mx;
  __syncthreads();
  if (tid == 0) {
    mxs = fmaxf(fmaxf(redf[0], redf[1]), fmaxf(redf[2], redf[3]));
    M0[n] = mxs;
  }
  __syncthreads();
  float mxa = mxs;
  double s = 0.0;
  for (int m = tid; m < M_; m += 256) s += (double)expf(L0[n * M_ + m] - mxa);
  for (int off = 32; off > 0; off >>= 1) s += __shfl_down(s, off, 64);
  if ((tid & 63) == 0) redd[tid >> 6] = s;
  __syncthreads();
  if (tid == 0) SumE0[n] = redd[0] + redd[1] + redd[2] + redd[3];
}

// ---------------------------------------------------------------------------
// K3b: ctxpart[ks][n][d] = sum_{m in ks-range} exp(L0[n][m]-M0[n]) * memory[m][d]
// split-K (8 ways) for parallelism; K3c reduces.
// ---------------------------------------------------------------------------
__global__ __launch_bounds__(256) void k_ctxpart(
    const float* __restrict__ L0, const float* __restrict__ M0,
    const float* __restrict__ mem, float* __restrict__ ctxp) {
  int ks = blockIdx.x;            // 0..7
  int n0 = blockIdx.y * 32;       // 8 tiles
  int d0 = blockIdx.z * 64;       // 4 tiles
  int tid = threadIdx.x;
  __shared__ float Et[64 * 32];   // [kk][nr]
  __shared__ float mTl[64 * 64];  // [kk][dd]
  __shared__ float Msh[32];
  if (tid < 32) Msh[tid] = M0[n0 + tid];
  const int lane = tid & 63, wv = tid >> 6;
  const int tx = lane & 15, ty = lane >> 4;
  const int ng = (wv * 4 + ty) * 2;  // 0..30 step 2
  const int dg = tx * 4;
  float acc[2][4] = {{0, 0, 0, 0}, {0, 0, 0, 0}};
  for (int kc = 0; kc < 4; ++kc) {
    int kb = ks * 256 + kc * 64;
    __syncthreads();
#pragma unroll
    for (int j = 0; j < 8; ++j) {
      int ii = tid + 256 * j;
      int nr = ii & 31, kk = ii >> 5;
      Et[kk * 32 + nr] = expf(L0[(n0 + nr) * M_ + kb + kk] - Msh[nr]);
    }
    {
      int r = tid & 63, c = tid >> 6;
#pragma unroll
      for (int j = 0; j < 4; ++j) {
        int c4 = (c * 4 + j) * 4;
        *(float4*)&mTl[r * 64 + c4] = *(const float4*)&mem[(kb + r) * D_ + d0 + c4];
      }
    }
    __syncthreads();
#pragma unroll 4
    for (int kk = 0; kk < 64; ++kk) {
      float4 mv = *(const float4*)&mTl[kk * 64 + dg];
      float e0v = Et[kk * 32 + ng], e1v = Et[kk * 32 + ng + 1];
      acc[0][0] = fmaf(e0v, mv.x, acc[0][0]); acc[0][1] = fmaf(e0v, mv.y, acc[0][1]);
      acc[0][2] = fmaf(e0v, mv.z, acc[0][2]); acc[0][3] = fmaf(e0v, mv.w, acc[0][3]);
      acc[1][0] = fmaf(e1v, mv.x, acc[1][0]); acc[1][1] = fmaf(e1v, mv.y, acc[1][1]);
      acc[1][2] = fmaf(e1v, mv.z, acc[1][2]); acc[1][3] = fmaf(e1v, mv.w, acc[1][3]);
    }
  }
#pragma unroll
  for (int i = 0; i < 2; ++i) {
    int n = n0 + ng + i;
    *(float4*)&ctxp[((size_t)ks * N_ + n) * D_ + d0 + dg] =
        make_float4(acc[i][0], acc[i][1], acc[i][2], acc[i][3]);
  }
}

__global__ void k_ctxreduce(const float* __restrict__ ctxp, float* __restrict__ CTX0) {
  int idx = blockIdx.x * 256 + threadIdx.x;  // N_*D_ = 65536
  float s = 0.f;
#pragma unroll
  for (int ks = 0; ks < 8; ++ks) s += ctxp[(size_t)ks * N_ * D_ + idx];
  CTX0[idx] = s;
}

// ---------------------------------------------------------------------------
// K4: per n: full bitonic sort of (L0, idx) descending (tie: lower idx first),
// emit top-256 values + indices.
// ---------------------------------------------------------------------------
__global__ __launch_bounds__(256) void k_top256(const float* __restrict__ L0,
                                                float* __restrict__ topv,
                                                int* __restrict__ topi) {
  int n = blockIdx.x, tid = threadIdx.x;
  __shared__ float v[M_];
  __shared__ short ix[M_];
  for (int m = tid; m < M_; m += 256) {
    v[m] = L0[n * M_ + m];
    ix[m] = (short)m;
  }
  __syncthreads();
  for (int size = 2; size <= M_; size <<= 1) {
    for (int stride = size >> 1; stride > 0; stride >>= 1) {
      for (int i = tid; i < M_ / 2; i += 256) {
        int pos = 2 * i - (i & (stride - 1));
        int j = pos + stride;
        bool desc = ((pos & size) == 0);
        float va = v[pos], vb = v[j];
        short ia = ix[pos], ib = ix[j];
        bool aGreater = (va > vb) || (va == vb && ia < ib);
        bool doSwap = desc ? !aGreater : aGreater;
        if (doSwap) { v[pos] = vb; v[j] = va; ix[pos] = ib; ix[j] = ia; }
      }
      __syncthreads();
    }
  }
  topv[n * TOPC + tid] = v[tid];
  topi[n * TOPC + tid] = (int)ix[tid];
}

// ---------------------------------------------------------------------------
// K5: the sequential scan. One block per batch, 1024 threads. No cross-block
// communication at all. Touched-row delta state in memcur[b][slot][D] (global,
// L2-resident), slot map in LDS.
// ---------------------------------------------------------------------------
__global__ __launch_bounds__(1024, 1) void k_scan(
    const float* __restrict__ x, const float* __restrict__ mem0,
    const float* __restrict__ Wv, const float* __restrict__ bv,
    const float* __restrict__ Wg, const float* __restrict__ bg,
    const float* __restrict__ qt, const float* __restrict__ qbk,
    const float* __restrict__ xgp, const float* __restrict__ L0,
    const float* __restrict__ M0, const double* __restrict__ SumE0,
    const float* __restrict__ CTX0, const float* __restrict__ topv,
    const int* __restrict__ topi, float* __restrict__ memcur,
    float* __restrict__ out) {
  const int b = blockIdx.x;
  const int tid = threadIdx.x;
  const int lane = tid & 63;
  const int wvid = tid >> 6;

  __shared__ float qt_s[D_], xt_s[D_], g_s[D_], ctx_s[D_], out_s[D_];
  __shared__ short tpos[M_];
  __shared__ int Tlist[NSLOT];
  __shared__ float curE[NSLOT], e0s[NSLOT];
  __shared__ float candV[NCAND];
  __shared__ int candI[NCAND];
  __shared__ float p1[1024];
  __shared__ double dpart[4 * D_];
  __shared__ float fpart[4 * D_];
  __shared__ double redd[16];
  __shared__ double esum_sh;
  __shared__ float c_sh, qbk_sh;
  __shared__ double sum0_sh;
  __shared__ int Tcount;
  __shared__ int selIdx[TK], selSlot[TK], selFresh[TK];

  for (int m = tid; m < M_; m += 1024) tpos[m] = -1;
  if (tid == 0) Tcount = 0;
  __syncthreads();

  for (int t = 0; t < S_; ++t) {
    const int n = t * B_ + b;
    const int Tc = Tcount;  // stable: last write was before the closing sync
    if (tid < D_) {
      qt_s[tid] = qt[n * D_ + tid];
      xt_s[tid] = x[(b * S_ + t) * D_ + tid];
    }
    if (tid == 0) {
      c_sh = M0[n];
      sum0_sh = SumE0[n];
      qbk_sh = qbk[n];
    }
    __syncthreads();

    // ---- phase 1: current logits for touched slots (4 threads per slot)
    {
      int s = tid >> 2, part = tid & 3;
      float a = 0.f;
      if (s < Tc) {
        const float* row = &memcur[((size_t)(b * NSLOT + s)) * D_ + part * 64];
        const float* q4 = &qt_s[part * 64];
#pragma unroll
        for (int j = 0; j < 64; j += 4) {
          float4 mv = *(const float4*)&row[j];
          float4 qv = *(const float4*)&q4[j];
          a = fmaf(mv.x, qv.x, a); a = fmaf(mv.y, qv.y, a);
          a = fmaf(mv.z, qv.z, a); a = fmaf(mv.w, qv.w, a);
        }
      }
      p1[tid] = a;
    }
    // top-256 candidate prep (reads tpos as of start-of-step)
    if (tid < TOPC) {
      int ii = topi[n * TOPC + tid];
      bool fresh = (tpos[ii] < 0);
      candV[NSLOT + tid] = fresh ? topv[n * TOPC + tid] : -INFINITY;
      candI[NSLOT + tid] = fresh ? ii : 0x7FFFFFFF;
    }
    __syncthreads();

    // ---- phase 1b: finalize per-slot values
    if (tid < NSLOT) {
      if (tid < Tc) {
        float dot = p1[tid * 4 + 0] + p1[tid * 4 + 1] + p1[tid * 4 + 2] + p1[tid * 4 + 3];
        float cur = (dot + qbk_sh) * 0.0625f;
        int m = Tlist[tid];
        curE[tid] = expf(cur - c_sh);
        e0s[tid] = expf(L0[(size_t)n * M_ + m] - c_sh);
        candV[tid] = cur;
        candI[tid] = m;
      } else {
        candV[tid] = -INFINITY;
        candI[tid] = 0x7FFFFFFF;
      }
    }
    __syncthreads();

    // ---- phase 2: denom (fp64) and ctx corrections (fp64)
    {
      double myv = 0.0;
      if (tid < Tc) myv = (double)curE[tid] - (double)e0s[tid];
      for (int off = 32; off > 0; off >>= 1) myv += __shfl_down(myv, off, 64);
      if (lane == 0) redd[wvid] = myv;
    }
    __syncthreads();
    if (tid == 0) {
      double ssum = sum0_sh;
      for (int w = 0; w < 16; ++w) ssum += redd[w];
      esum_sh = ssum;
    }
    {
      int d = tid & 255, part = tid >> 8;
      double corr = 0.0;
      for (int s = part; s < Tc; s += 4) {
        float mc = memcur[((size_t)(b * NSLOT + s)) * D_ + d];
        float mo = mem0[(size_t)Tlist[s] * D_ + d];
        corr += (double)curE[s] * (double)mc - (double)e0s[s] * (double)mo;
      }
      dpart[part * D_ + d] = corr;
    }
    __syncthreads();
    if (tid < D_) {
      double cx = ((double)CTX0[(size_t)n * D_ + tid] + dpart[tid] + dpart[D_ + tid] +
                   dpart[2 * D_ + tid] + dpart[3 * D_ + tid]) / esum_sh;
      ctx_s[tid] = (float)cx;
    }
    __syncthreads();

    // ---- phase 3: out = ctx@Wv + bv ; g = sigmoid(xgpre + out@Wg_bot + bg)
    {
      int d = tid & 255, rep = tid >> 8;
      float a = 0.f;
#pragma unroll 8
      for (int i = 0; i < 64; ++i)
        a = fmaf(ctx_s[rep * 64 + i], Wv[(size_t)(rep * 64 + i) * D_ + d], a);
      fpart[rep * D_ + d] = a;
    }
    __syncthreads();
    if (tid < D_) {
      float o = fpart[tid] + fpart[D_ + tid] + fpart[2 * D_ + tid] + fpart[3 * D_ + tid] + bv[tid];
      out_s[tid] = o;
      out[((size_t)b * S_ + t) * D_ + tid] = o;
    }
    __syncthreads();
    {
      int d = tid & 255, rep = tid >> 8;
      float a = 0.f;
#pragma unroll 8
      for (int i = 0; i < 64; ++i)
        a = fmaf(out_s[rep * 64 + i], Wg[(size_t)(D_ + rep * 64 + i) * D_ + d], a);
      fpart[rep * D_ + d] = a;
    }
    __syncthreads();
    if (tid < D_) {
      float gin = xgp[(size_t)n * D_ + tid] + fpart[tid] + fpart[D_ + tid] +
                  fpart[2 * D_ + tid] + fpart[3 * D_ + tid] + bg[tid];
      g_s[tid] = 1.0f / (1.0f + expf(-gin));
    }
    __syncthreads();

    if (t < S_ - 1) {
      // ---- phase 4: top-8 of 512 candidates (wave 0, 8 cands/lane, 8 rounds)
      if (wvid == 0) {
        float cv[8];
        int ci[8];
#pragma unroll
        for (int j = 0; j < 8; ++j) {
          cv[j] = candV[lane * 8 + j];
          ci[j] = candI[lane * 8 + j];
        }
        for (int r = 0; r < TK; ++r) {
          float bvv = cv[0];
          int bii = ci[0];
#pragma unroll
          for (int j = 1; j < 8; ++j)
            if (cv[j] > bvv || (cv[j] == bvv && ci[j] < bii)) { bvv = cv[j]; bii = ci[j]; }
          for (int off = 1; off < 64; off <<= 1) {
            float ov = __shfl_xor(bvv, off, 64);
            int oi = __shfl_xor(bii, off, 64);
            if (ov > bvv || (ov == bvv && oi < bii)) { bvv = ov; bii = oi; }
          }
          if (lane == 0) selIdx[r] = bii;
#pragma unroll
          for (int j = 0; j < 8; ++j)
            if (ci[j] == bii) { cv[j] = -INFINITY; ci[j] = 0x7FFFFFFF; }
        }
      }
      __syncthreads();

      // ---- phase 5: slot allocation + memory row updates
      if (tid == 0) {
        for (int k = 0; k < TK; ++k) {
          int m = selIdx[k];
          int s = tpos[m];
          if (s < 0) {
            s = Tcount; Tcount = s + 1;
            tpos[m] = (short)s; Tlist[s] = m;
            selFresh[k] = 1;
          } else selFresh[k] = 0;
          selSlot[k] = s;
        }
      }
      __syncthreads();
      {
        int d = tid & 255, part = tid >> 8;
#pragma unroll
        for (int kk = 0; kk < 2; ++kk) {
          int k = part * 2 + kk;
          int m = selIdx[k], s = selSlot[k];
          float oldv = selFresh[k] ? mem0[(size_t)m * D_ + d]
                                   : memcur[((size_t)(b * NSLOT + s)) * D_ + d];
          float gvv = g_s[d];
          memcur[((size_t)(b * NSLOT + s)) * D_ + d] = (1.0f - gvv) * oldv + gvv * xt_s[d];
        }
      }
      __syncthreads();
    }
  }
}

// ---------------------------------------------------------------------------
extern "C" void kernel_launch(void* const* d_in, const int* in_sizes, int n_in,
                              void* d_out, int out_size, void* d_ws, size_t ws_size,
                              hipStream_t stream) {
  const float* x = (const float*)d_in[0];
  const float* mem0 = (const float*)d_in[1];
  const float* Wq = (const float*)d_in[2];
  const float* bq = (const float*)d_in[3];
  const float* Wk = (const float*)d_in[4];
  const float* bk = (const float*)d_in[5];
  const float* Wv = (const float*)d_in[6];
  const float* bv = (const float*)d_in[7];
  const float* Wg = (const float*)d_in[8];
  const float* bg = (const float*)d_in[9];
  float* out = (float*)d_out;
  float* ws = (float*)d_ws;

  size_t o = 0;
  float* WkT = ws + o;  o += (size_t)D_ * D_;
  float* qt = ws + o;   o += (size_t)N_ * D_;
  float* qbk = ws + o;  o += N_;
  float* xgp = ws + o;  o += (size_t)N_ * D_;
  float* L0 = ws + o;   o += (size_t)N_ * M_;
  float* M0 = ws + o;   o += N_;
  double* SumE0 = (double*)(ws + o); o += 2 * N_;
  float* CTX0 = ws + o; o += (size_t)N_ * D_;
  float* ctxp = ws + o; o += (size_t)8 * N_ * D_;
  float* topv = ws + o; o += (size_t)N_ * TOPC;
  int* topi = (int*)(ws + o); o += (size_t)N_ * TOPC;
  float* memcur = ws + o; o += (size_t)B_ * NSLOT * D_;

  k_transpose<<<dim3(64), dim3(256), 0, stream>>>(Wk, WkT);
  k_qproj<<<dim3(N_), dim3(256), 0, stream>>>(x, Wq, bq, bk, WkT, Wg, qt, qbk, xgp);
  k_L0<<<dim3(M_ / 64, N_ / 64), dim3(256), 0, stream>>>(qt, mem0, qbk, L0);
  k_stats<<<dim3(N_), dim3(256), 0, stream>>>(L0, M0, SumE0);
  k_ctxpart<<<dim3(8, N_ / 32, D_ / 64), dim3(256), 0, stream>>>(L0, M0, mem0, ctxp);
  k_ctxreduce<<<dim3(N_), dim3(256), 0, stream>>>(ctxp, CTX0);
  k_top256<<<dim3(N_), dim3(256), 0, stream>>>(L0, topv, topi);
  k_scan<<<dim3(B_), dim3(1024), 0, stream>>>(x, mem0, Wv, bv, Wg, bg, qt, qbk, xgp,
                                              L0, M0, SumE0, CTX0, topv, topi, memcur, out);
}

// Round 2
// 678.600 us; speedup vs baseline: 1.1028x; 1.1028x over previous
//
#include <hip/hip_runtime.h>
#include <math.h>

// Problem constants
constexpr int B_ = 8, S_ = 32, D_ = 256, M_ = 2048;
constexpr int N_ = S_ * B_;          // 256 (t,b) pairs, n = t*B + b
constexpr int TK = 8;                // TOPK
constexpr int NSLOT = 256;           // max distinct touched rows (8*32)
constexpr int TOPC = 256;            // precomputed top-C of L0 per (t,b)
constexpr int NCAND = NSLOT + TOPC;  // 512
constexpr int KSPLIT = 4;            // ctxpart split-K

// ---------------------------------------------------------------------------
// K0: WkT[j][i] = Wk[i][j]
// ---------------------------------------------------------------------------
__global__ void k_transpose(const float* __restrict__ Wk, float* __restrict__ WkT) {
  __shared__ float tile[32][33];
  int bx = blockIdx.x & 7, by = blockIdx.x >> 3;
  int x0 = bx * 32, y0 = by * 32;
  int tx = threadIdx.x & 31, ty = threadIdx.x >> 5;
  for (int j = ty; j < 32; j += 8) tile[j][tx] = Wk[(y0 + j) * D_ + x0 + tx];
  __syncthreads();
  for (int j = ty; j < 32; j += 8) WkT[(x0 + j) * D_ + y0 + tx] = tile[tx][j];
}

// ---------------------------------------------------------------------------
// K1: per n=(t,b): q = xt@Wq+bq ; qt[d]=sum_i q[i]*WkT[i][d] ; qbk = q.bk ;
//     xgpre = xt @ Wg[0:D,:]
// ---------------------------------------------------------------------------
__global__ __launch_bounds__(256) void k_qproj(
    const float* __restrict__ x, const float* __restrict__ Wq,
    const float* __restrict__ bq, const float* __restrict__ bk,
    const float* __restrict__ WkT, const float* __restrict__ Wg,
    float* __restrict__ qt, float* __restrict__ qbk, float* __restrict__ xgp) {
  int n = blockIdx.x, tid = threadIdx.x;
  int t = n / B_, b = n % B_;
  __shared__ float xr[D_], qsh[D_];
  __shared__ float red[4];
  xr[tid] = x[(b * S_ + t) * D_ + tid];
  __syncthreads();
  float accq = bq[tid], accg = 0.f;
#pragma unroll 8
  for (int i = 0; i < D_; ++i) {
    float xv = xr[i];
    accq = fmaf(xv, Wq[i * D_ + tid], accq);
    accg = fmaf(xv, Wg[i * D_ + tid], accg);
  }
  qsh[tid] = accq;
  xgp[n * D_ + tid] = accg;
  float p = accq * bk[tid];
  for (int off = 32; off > 0; off >>= 1) p += __shfl_down(p, off, 64);
  if ((tid & 63) == 0) red[tid >> 6] = p;
  __syncthreads();
  float acct = 0.f;
#pragma unroll 8
  for (int i = 0; i < D_; ++i) acct = fmaf(qsh[i], WkT[i * D_ + tid], acct);
  qt[n * D_ + tid] = acct;
  if (tid == 0) qbk[n] = red[0] + red[1] + red[2] + red[3];
}

// ---------------------------------------------------------------------------
// K2: L0[n][m] = (memory[m] . qt[n] + qbk[n]) / 16
// ---------------------------------------------------------------------------
__global__ __launch_bounds__(256) void k_L0(
    const float* __restrict__ qt, const float* __restrict__ mem,
    const float* __restrict__ qbk, float* __restrict__ L0) {
  __shared__ float qtT[64 * 64];
  __shared__ float mT[64 * 64];
  const int tid = threadIdx.x;
  const int m0 = blockIdx.x * 64, n0 = blockIdx.y * 64;
  const int r = tid & 63, c = tid >> 6;
  const int lane = tid & 63, wv = tid >> 6;
  const int tx = lane & 15, ty = lane >> 4;
  const int mg = tx * 4, ng = (wv * 4 + ty) * 4;
  float acc[4][4];
#pragma unroll
  for (int i = 0; i < 4; ++i)
#pragma unroll
    for (int j = 0; j < 4; ++j) acc[i][j] = 0.f;
  for (int kc = 0; kc < 4; ++kc) {
    __syncthreads();
#pragma unroll
    for (int it = 0; it < 4; ++it) {
      int kq = (c * 4 + it) * 4;
      float4 a = *(const float4*)&qt[(n0 + r) * D_ + kc * 64 + kq];
      qtT[(kq + 0) * 64 + r] = a.x; qtT[(kq + 1) * 64 + r] = a.y;
      qtT[(kq + 2) * 64 + r] = a.z; qtT[(kq + 3) * 64 + r] = a.w;
      float4 bm = *(const float4*)&mem[(m0 + r) * D_ + kc * 64 + kq];
      mT[(kq + 0) * 64 + r] = bm.x; mT[(kq + 1) * 64 + r] = bm.y;
      mT[(kq + 2) * 64 + r] = bm.z; mT[(kq + 3) * 64 + r] = bm.w;
    }
    __syncthreads();
#pragma unroll 4
    for (int k = 0; k < 64; ++k) {
      float4 av = *(const float4*)&qtT[k * 64 + ng];
      float4 bv4 = *(const float4*)&mT[k * 64 + mg];
      acc[0][0] = fmaf(av.x, bv4.x, acc[0][0]); acc[0][1] = fmaf(av.x, bv4.y, acc[0][1]);
      acc[0][2] = fmaf(av.x, bv4.z, acc[0][2]); acc[0][3] = fmaf(av.x, bv4.w, acc[0][3]);
      acc[1][0] = fmaf(av.y, bv4.x, acc[1][0]); acc[1][1] = fmaf(av.y, bv4.y, acc[1][1]);
      acc[1][2] = fmaf(av.y, bv4.z, acc[1][2]); acc[1][3] = fmaf(av.y, bv4.w, acc[1][3]);
      acc[2][0] = fmaf(av.z, bv4.x, acc[2][0]); acc[2][1] = fmaf(av.z, bv4.y, acc[2][1]);
      acc[2][2] = fmaf(av.z, bv4.z, acc[2][2]); acc[2][3] = fmaf(av.z, bv4.w, acc[2][3]);
      acc[3][0] = fmaf(av.w, bv4.x, acc[3][0]); acc[3][1] = fmaf(av.w, bv4.y, acc[3][1]);
      acc[3][2] = fmaf(av.w, bv4.z, acc[3][2]); acc[3][3] = fmaf(av.w, bv4.w, acc[3][3]);
    }
  }
#pragma unroll
  for (int i = 0; i < 4; ++i) {
    int n = n0 + ng + i;
    float qbv = qbk[n];
    float4 o;
    o.x = (acc[i][0] + qbv) * 0.0625f; o.y = (acc[i][1] + qbv) * 0.0625f;
    o.z = (acc[i][2] + qbv) * 0.0625f; o.w = (acc[i][3] + qbv) * 0.0625f;
    *(float4*)&L0[n * M_ + m0 + mg] = o;
  }
}

// ---------------------------------------------------------------------------
// K3: fused full bitonic sort (desc, tie idx asc) + top-256 + M0 + SumE0(fp64)
// ---------------------------------------------------------------------------
__global__ __launch_bounds__(256) void k_sortstats(const float* __restrict__ L0,
                                                   float* __restrict__ topv,
                                                   int* __restrict__ topi,
                                                   float* __restrict__ M0,
                                                   double* __restrict__ SumE0) {
  int n = blockIdx.x, tid = threadIdx.x;
  __shared__ float v[M_];
  __shared__ short ix[M_];
  __shared__ double redd[4];
  for (int m = tid; m < M_; m += 256) {
    v[m] = L0[(size_t)n * M_ + m];
    ix[m] = (short)m;
  }
  __syncthreads();
  for (int size = 2; size <= M_; size <<= 1) {
    for (int stride = size >> 1; stride > 0; stride >>= 1) {
      for (int i = tid; i < M_ / 2; i += 256) {
        int pos = 2 * i - (i & (stride - 1));
        int j = pos + stride;
        bool desc = ((pos & size) == 0);
        float va = v[pos], vb2 = v[j];
        short ia = ix[pos], ib = ix[j];
        bool aG = (va > vb2) || (va == vb2 && ia < ib);
        if (desc ? !aG : aG) { v[pos] = vb2; v[j] = va; ix[pos] = ib; ix[j] = ia; }
      }
      __syncthreads();
    }
  }
  topv[n * TOPC + tid] = v[tid];
  topi[n * TOPC + tid] = (int)ix[tid];
  float mx = v[0];
  if (tid == 0) M0[n] = mx;
  double s = 0.0;
  for (int m = tid; m < M_; m += 256) s += (double)expf(v[m] - mx);
  for (int off = 32; off > 0; off >>= 1) s += __shfl_down(s, off, 64);
  if ((tid & 63) == 0) redd[tid >> 6] = s;
  __syncthreads();
  if (tid == 0) SumE0[n] = redd[0] + redd[1] + redd[2] + redd[3];
}

// ---------------------------------------------------------------------------
// K4: ctxpart[ks][n][d] = sum over ks's K-range of exp(L0-M0)*memory  (split-4)
// ---------------------------------------------------------------------------
__global__ __launch_bounds__(256) void k_ctxpart(
    const float* __restrict__ L0, const float* __restrict__ M0,
    const float* __restrict__ mem, float* __restrict__ ctxp) {
  int ks = blockIdx.x;            // 0..3
  int n0 = blockIdx.y * 32;
  int d0 = blockIdx.z * 64;
  int tid = threadIdx.x;
  __shared__ float Et[64 * 32];
  __shared__ float mTl[64 * 64];
  __shared__ float Msh[32];
  if (tid < 32) Msh[tid] = M0[n0 + tid];
  const int lane = tid & 63, wv = tid >> 6;
  const int tx = lane & 15, ty = lane >> 4;
  const int ng = (wv * 4 + ty) * 2;
  const int dg = tx * 4;
  float acc[2][4] = {{0, 0, 0, 0}, {0, 0, 0, 0}};
  for (int kc = 0; kc < 8; ++kc) {
    int kb = ks * 512 + kc * 64;
    __syncthreads();
#pragma unroll
    for (int j = 0; j < 8; ++j) {
      int ii = tid + 256 * j;
      int nr = ii & 31, kk = ii >> 5;
      Et[kk * 32 + nr] = expf(L0[(n0 + nr) * M_ + kb + kk] - Msh[nr]);
    }
    {
      int r = tid & 63, c = tid >> 6;
#pragma unroll
      for (int j = 0; j < 4; ++j) {
        int c4 = (c * 4 + j) * 4;
        *(float4*)&mTl[r * 64 + c4] = *(const float4*)&mem[(kb + r) * D_ + d0 + c4];
      }
    }
    __syncthreads();
#pragma unroll 4
    for (int kk = 0; kk < 64; ++kk) {
      float4 mv = *(const float4*)&mTl[kk * 64 + dg];
      float e0v = Et[kk * 32 + ng], e1v = Et[kk * 32 + ng + 1];
      acc[0][0] = fmaf(e0v, mv.x, acc[0][0]); acc[0][1] = fmaf(e0v, mv.y, acc[0][1]);
      acc[0][2] = fmaf(e0v, mv.z, acc[0][2]); acc[0][3] = fmaf(e0v, mv.w, acc[0][3]);
      acc[1][0] = fmaf(e1v, mv.x, acc[1][0]); acc[1][1] = fmaf(e1v, mv.y, acc[1][1]);
      acc[1][2] = fmaf(e1v, mv.z, acc[1][2]); acc[1][3] = fmaf(e1v, mv.w, acc[1][3]);
    }
  }
#pragma unroll
  for (int i = 0; i < 2; ++i) {
    int n = n0 + ng + i;
    *(float4*)&ctxp[((size_t)ks * N_ + n) * D_ + d0 + dg] =
        make_float4(acc[i][0], acc[i][1], acc[i][2], acc[i][3]);
  }
}

__global__ void k_ctxreduce(const float* __restrict__ ctxp, float* __restrict__ CTX0) {
  int idx = blockIdx.x * 256 + threadIdx.x;
  float s = 0.f;
#pragma unroll
  for (int ks = 0; ks < KSPLIT; ++ks) s += ctxp[(size_t)ks * N_ * D_ + idx];
  CTX0[idx] = s;
}

// ---------------------------------------------------------------------------
// K5: WvWgB[i][d] = sum_j Wv[i][j]*Wg[D+j][d]  (blocks 0..15) ;
//     bvg[d] = bg[d] + sum_j bv[j]*Wg[D+j][d]  (block 16)
// ---------------------------------------------------------------------------
__global__ __launch_bounds__(256) void k_wvwg(const float* __restrict__ Wv,
                                              const float* __restrict__ Wg,
                                              const float* __restrict__ bv,
                                              const float* __restrict__ bg,
                                              float* __restrict__ WvWgB,
                                              float* __restrict__ bvg) {
  int blk = blockIdx.x;
  int tid = threadIdx.x;
  if (blk == 16) {
    float a = bg[tid];
#pragma unroll 8
    for (int j = 0; j < D_; ++j) a = fmaf(bv[j], Wg[(size_t)(D_ + j) * D_ + tid], a);
    bvg[tid] = a;
    return;
  }
  int i0 = (blk & 3) * 64, d0 = (blk >> 2) * 64;
  __shared__ float At[64 * 64];  // [j][i]
  __shared__ float Bt[64 * 64];  // [j][d]
  const int r = tid & 63, c = tid >> 6;
  const int lane = tid & 63, wvv = tid >> 6;
  const int tx = lane & 15, ty = lane >> 4;
  const int dg = tx * 4, ig = (wvv * 4 + ty) * 4;
  float acc[4][4];
#pragma unroll
  for (int i = 0; i < 4; ++i)
#pragma unroll
    for (int j = 0; j < 4; ++j) acc[i][j] = 0.f;
  for (int kc = 0; kc < 4; ++kc) {
    __syncthreads();
#pragma unroll
    for (int it = 0; it < 4; ++it) {
      int jq = (c * 4 + it) * 4;
      float4 a = *(const float4*)&Wv[(i0 + r) * D_ + kc * 64 + jq];
      At[(jq + 0) * 64 + r] = a.x; At[(jq + 1) * 64 + r] = a.y;
      At[(jq + 2) * 64 + r] = a.z; At[(jq + 3) * 64 + r] = a.w;
      int dq = (c * 4 + it) * 4;
      *(float4*)&Bt[r * 64 + dq] =
          *(const float4*)&Wg[(size_t)(D_ + kc * 64 + r) * D_ + d0 + dq];
    }
    __syncthreads();
#pragma unroll 4
    for (int j = 0; j < 64; ++j) {
      float4 av = *(const float4*)&At[j * 64 + ig];
      float4 bv4 = *(const float4*)&Bt[j * 64 + dg];
      acc[0][0] = fmaf(av.x, bv4.x, acc[0][0]); acc[0][1] = fmaf(av.x, bv4.y, acc[0][1]);
      acc[0][2] = fmaf(av.x, bv4.z, acc[0][2]); acc[0][3] = fmaf(av.x, bv4.w, acc[0][3]);
      acc[1][0] = fmaf(av.y, bv4.x, acc[1][0]); acc[1][1] = fmaf(av.y, bv4.y, acc[1][1]);
      acc[1][2] = fmaf(av.y, bv4.z, acc[1][2]); acc[1][3] = fmaf(av.y, bv4.w, acc[1][3]);
      acc[2][0] = fmaf(av.z, bv4.x, acc[2][0]); acc[2][1] = fmaf(av.z, bv4.y, acc[2][1]);
      acc[2][2] = fmaf(av.z, bv4.z, acc[2][2]); acc[2][3] = fmaf(av.z, bv4.w, acc[2][3]);
      acc[3][0] = fmaf(av.w, bv4.x, acc[3][0]); acc[3][1] = fmaf(av.w, bv4.y, acc[3][1]);
      acc[3][2] = fmaf(av.w, bv4.z, acc[3][2]); acc[3][3] = fmaf(av.w, bv4.w, acc[3][3]);
    }
  }
#pragma unroll
  for (int i = 0; i < 4; ++i) {
    *(float4*)&WvWgB[(size_t)(i0 + ig + i) * D_ + d0 + dg] =
        make_float4(acc[i][0], acc[i][1], acc[i][2], acc[i][3]);
  }
}

// ---------------------------------------------------------------------------
// K6: the scan. One block/batch, 1024 threads, 5 barriers/step.
// ---------------------------------------------------------------------------
__global__ __launch_bounds__(1024, 1) void k_scan(
    const float* __restrict__ x, const float* __restrict__ mem0,
    const float* __restrict__ Wv, const float* __restrict__ bv,
    const float* __restrict__ WvWgB, const float* __restrict__ bvg,
    const float* __restrict__ qt, const float* __restrict__ qbk,
    const float* __restrict__ xgp, const float* __restrict__ L0,
    const float* __restrict__ M0, const double* __restrict__ SumE0,
    const float* __restrict__ CTX0, const float* __restrict__ topv,
    const int* __restrict__ topi, float* __restrict__ memcur,
    float* __restrict__ out) {
  const int b = blockIdx.x;
  const int tid = threadIdx.x;
  const int lane = tid & 63;
  const int wv = tid >> 6;

  __shared__ short tpos[M_];
  __shared__ int Tlist[NSLOT];
  __shared__ float curE[NSLOT], e0sA[NSLOT];
  __shared__ float candV[NCAND];
  __shared__ int candI[NCAND];
  __shared__ float dpart[15][D_];
  __shared__ float fpart[16][D_];
  __shared__ float qt_s[2][D_], xt_s[2][D_];
  __shared__ float g_s[D_];
  __shared__ float CTX0_s[D_], xgp_s[D_];
  __shared__ float bv_s[D_], bvg_s[D_];
  __shared__ float Msc[S_], qbks[S_];
  __shared__ double sum0s[S_];
  __shared__ float inv_esum;
  __shared__ int Tcount;
  __shared__ int selIdx[TK], selSlot[TK], selFresh[TK];

  // ---- preload
  for (int m = tid; m < M_; m += 1024) tpos[m] = -1;
  if (tid < S_) {
    Msc[tid] = M0[tid * B_ + b];
    qbks[tid] = qbk[tid * B_ + b];
  } else if (tid < 2 * S_) {
    sum0s[tid - S_] = SumE0[(tid - S_) * B_ + b];
  }
  if (tid >= 64 && tid < 64 + D_) {
    bv_s[tid - 64] = bv[tid - 64];
  } else if (tid < 64 + 2 * D_) {
    if (tid >= 64 + D_) bvg_s[tid - 64 - D_] = bvg[tid - 64 - D_];
  } else if (tid < 64 + 2 * D_ + 64) {
    int j = tid - (64 + 2 * D_);
    ((float4*)qt_s[0])[j] = ((const float4*)qt)[(size_t)b * 64 + j];  // n=0*B+b
  } else if (tid < 64 + 2 * D_ + 128) {
    int j = tid - (64 + 2 * D_ + 64);
    ((float4*)xt_s[0])[j] = ((const float4*)x)[((size_t)b * S_) * 64 + j];  // t=0
  }
  if (tid == 0) Tcount = 0;
  __syncthreads();

  for (int t = 0; t < S_; ++t) {
    const int n = t * B_ + b;
    const int par = t & 1;
    const int Tc = Tcount;
    const float c0 = Msc[t];
    const float qb = qbks[t];

    // ===== P1: slot dots + finalize + candprep + prefetch =====
    {
      int s = tid >> 2, part = tid & 3;
      float a = 0.f;
      if (s < Tc) {
        const float4* row = (const float4*)&memcur[((size_t)(b * NSLOT + s)) * D_] + part * 16;
        const float4* q4 = (const float4*)&qt_s[par][part * 64];
#pragma unroll
        for (int j = 0; j < 16; ++j) {
          float4 mv = row[j];
          float4 qv = q4[j];
          a = fmaf(mv.x, qv.x, a); a = fmaf(mv.y, qv.y, a);
          a = fmaf(mv.z, qv.z, a); a = fmaf(mv.w, qv.w, a);
        }
      }
      a += __shfl_xor(a, 1, 64);
      a += __shfl_xor(a, 2, 64);
      if (part == 0) {
        if (s < Tc) {
          float cur = (a + qb) * 0.0625f;
          int m = Tlist[s];
          curE[s] = expf(cur - c0);
          e0sA[s] = expf(L0[(size_t)n * M_ + m] - c0);
          candV[s] = cur;
          candI[s] = m;
        } else {
          candV[s] = -INFINITY;
          candI[s] = 0x7FFFFFFF;
        }
      } else if (part == 1) {
        int j = s;
        int ii = topi[n * TOPC + j];
        bool fresh = (tpos[ii] < 0);
        candV[NSLOT + j] = fresh ? topv[n * TOPC + j] : -INFINITY;
        candI[NSLOT + j] = fresh ? ii : 0x7FFFFFFF;
      } else if (part == 2) {
        if (s < 64) ((float4*)CTX0_s)[s] = ((const float4*)CTX0)[(size_t)n * 64 + s];
        else if (s < 128) ((float4*)xgp_s)[s - 64] = ((const float4*)xgp)[(size_t)n * 64 + (s - 64)];
      } else {
        if (t + 1 < S_) {
          if (s < 64)
            ((float4*)qt_s[par ^ 1])[s] = ((const float4*)qt)[(size_t)(n + B_) * 64 + s];
          else if (s < 128)
            ((float4*)xt_s[par ^ 1])[s - 64] =
                ((const float4*)x)[((size_t)b * S_ + t + 1) * 64 + (s - 64)];
        }
      }
    }
    __syncthreads();  // B1

    // ===== P3: wave15 top-8 + alloc + denom  |  waves 0-14 correction pass =====
    if (wv == 15) {
      float cv[8];
      int ci[8];
#pragma unroll
      for (int j = 0; j < 8; ++j) {
        cv[j] = candV[lane * 8 + j];
        ci[j] = candI[lane * 8 + j];
      }
      for (int r = 0; r < TK; ++r) {
        float bvv = cv[0];
        int bii = ci[0];
#pragma unroll
        for (int j = 1; j < 8; ++j)
          if (cv[j] > bvv || (cv[j] == bvv && ci[j] < bii)) { bvv = cv[j]; bii = ci[j]; }
#pragma unroll
        for (int off = 1; off < 64; off <<= 1) {
          float ov = __shfl_xor(bvv, off, 64);
          int oi = __shfl_xor(bii, off, 64);
          if (ov > bvv || (ov == bvv && oi < bii)) { bvv = ov; bii = oi; }
        }
        if (lane == 0) selIdx[r] = bii;
#pragma unroll
        for (int j = 0; j < 8; ++j)
          if (ci[j] == bii) { cv[j] = -INFINITY; ci[j] = 0x7FFFFFFF; }
      }
      if (lane == 0) {
        int tc = Tcount;
        for (int k = 0; k < TK; ++k) {
          int m = selIdx[k];
          int s = tpos[m];
          if (s < 0) {
            s = tc++;
            tpos[m] = (short)s;
            Tlist[s] = m;
            selFresh[k] = 1;
          } else
            selFresh[k] = 0;
          selSlot[k] = s;
        }
        Tcount = tc;
      }
      double ds = 0.0;
      for (int s = lane; s < Tc; s += 64) ds += (double)curE[s] - (double)e0sA[s];
      for (int off = 32; off > 0; off >>= 1) ds += __shfl_down(ds, off, 64);
      if (lane == 0) inv_esum = (float)(1.0 / (sum0s[t] + ds));
    } else {
      int d4 = lane, sp = wv;  // sp 0..14
      float4 acc = make_float4(0.f, 0.f, 0.f, 0.f);
      for (int s = sp; s < Tc; s += 15) {
        float e1 = curE[s], e0 = e0sA[s];
        int m = Tlist[s];
        float4 mc = ((const float4*)memcur)[((size_t)(b * NSLOT + s)) * 64 + d4];
        float4 mo = ((const float4*)mem0)[(size_t)m * 64 + d4];
        acc.x = fmaf(e1, mc.x, acc.x); acc.x = fmaf(-e0, mo.x, acc.x);
        acc.y = fmaf(e1, mc.y, acc.y); acc.y = fmaf(-e0, mo.y, acc.y);
        acc.z = fmaf(e1, mc.z, acc.z); acc.z = fmaf(-e0, mo.z, acc.z);
        acc.w = fmaf(e1, mc.w, acc.w); acc.w = fmaf(-e0, mo.w, acc.w);
      }
      ((float4*)dpart[sp])[d4] = acc;
    }
    __syncthreads();  // B3

    // ===== P5: per-wave num reconstruction (shfl broadcast) + fused GEMV =====
    {
      int kp = wv & 7, k0 = kp * 32;
      float mynum = 0.f;
      if (lane < 32) {
        int k = k0 + lane;
        float nv = CTX0_s[k];
#pragma unroll
        for (int p = 0; p < 15; ++p) nv += dpart[p][k];
        mynum = nv;
      }
      const float4* Mp = (wv < 8) ? (const float4*)Wv : (const float4*)WvWgB;
      float4 acc = make_float4(0.f, 0.f, 0.f, 0.f);
#pragma unroll 8
      for (int i = 0; i < 32; ++i) {
        float nv = __shfl(mynum, i, 64);
        float4 w4 = Mp[(size_t)(k0 + i) * 64 + lane];
        acc.x = fmaf(nv, w4.x, acc.x); acc.y = fmaf(nv, w4.y, acc.y);
        acc.z = fmaf(nv, w4.z, acc.z); acc.w = fmaf(nv, w4.w, acc.w);
      }
      ((float4*)fpart[wv])[lane] = acc;
    }
    __syncthreads();  // B5

    // ===== P6: finalize out & gate =====
    if (tid < D_) {
      int d = tid;
      float o = 0.f;
#pragma unroll
      for (int p = 0; p < 8; ++p) o += fpart[p][d];
      o = o * inv_esum + bv_s[d];
      out[((size_t)b * S_ + t) * D_ + d] = o;
    } else if (tid < 2 * D_) {
      int d = tid - D_;
      float gg = 0.f;
#pragma unroll
      for (int p = 8; p < 16; ++p) gg += fpart[p][d];
      float gin = xgp_s[d] + gg * inv_esum + bvg_s[d];
      g_s[d] = 1.0f / (1.0f + expf(-gin));
    }
    __syncthreads();  // B6

    // ===== P7: memory row updates =====
    if (t < S_ - 1) {
      int d = tid & 255, part = tid >> 8;
#pragma unroll
      for (int kk = 0; kk < 2; ++kk) {
        int k = part * 2 + kk;
        int m = selIdx[k], s = selSlot[k];
        float oldv = selFresh[k] ? mem0[(size_t)m * D_ + d]
                                 : memcur[((size_t)(b * NSLOT + s)) * D_ + d];
        float gv = g_s[d];
        memcur[((size_t)(b * NSLOT + s)) * D_ + d] = (1.0f - gv) * oldv + gv * xt_s[par][d];
      }
      __syncthreads();  // B7
    }
  }
}

// ---------------------------------------------------------------------------
extern "C" void kernel_launch(void* const* d_in, const int* in_sizes, int n_in,
                              void* d_out, int out_size, void* d_ws, size_t ws_size,
                              hipStream_t stream) {
  const float* x = (const float*)d_in[0];
  const float* mem0 = (const float*)d_in[1];
  const float* Wq = (const float*)d_in[2];
  const float* bq = (const float*)d_in[3];
  const float* Wk = (const float*)d_in[4];
  const float* bk = (const float*)d_in[5];
  const float* Wv = (const float*)d_in[6];
  const float* bv = (const float*)d_in[7];
  const float* Wg = (const float*)d_in[8];
  const float* bg = (const float*)d_in[9];
  float* out = (float*)d_out;
  float* ws = (float*)d_ws;

  size_t o = 0;
  float* WkT = ws + o;   o += (size_t)D_ * D_;
  float* qt = ws + o;    o += (size_t)N_ * D_;
  float* qbk = ws + o;   o += N_;
  float* xgp = ws + o;   o += (size_t)N_ * D_;
  float* L0 = ws + o;    o += (size_t)N_ * M_;
  float* M0 = ws + o;    o += N_;
  double* SumE0 = (double*)(ws + o); o += 2 * N_;
  float* CTX0 = ws + o;  o += (size_t)N_ * D_;
  float* ctxp = ws + o;  o += (size_t)KSPLIT * N_ * D_;
  float* topv = ws + o;  o += (size_t)N_ * TOPC;
  int* topi = (int*)(ws + o); o += (size_t)N_ * TOPC;
  float* WvWgB = ws + o; o += (size_t)D_ * D_;
  float* bvg = ws + o;   o += D_;
  float* memcur = ws + o; o += (size_t)B_ * NSLOT * D_;

  k_transpose<<<dim3(64), dim3(256), 0, stream>>>(Wk, WkT);
  k_qproj<<<dim3(N_), dim3(256), 0, stream>>>(x, Wq, bq, bk, WkT, Wg, qt, qbk, xgp);
  k_L0<<<dim3(M_ / 64, N_ / 64), dim3(256), 0, stream>>>(qt, mem0, qbk, L0);
  k_sortstats<<<dim3(N_), dim3(256), 0, stream>>>(L0, topv, topi, M0, SumE0);
  k_ctxpart<<<dim3(KSPLIT, N_ / 32, D_ / 64), dim3(256), 0, stream>>>(L0, M0, mem0, ctxp);
  k_ctxreduce<<<dim3(N_), dim3(256), 0, stream>>>(ctxp, CTX0);
  k_wvwg<<<dim3(17), dim3(256), 0, stream>>>(Wv, Wg, bv, bg, WvWgB, bvg);
  k_scan<<<dim3(B_), dim3(1024), 0, stream>>>(x, mem0, Wv, bv, WvWgB, bvg, qt, qbk, xgp,
                                              L0, M0, SumE0, CTX0, topv, topi, memcur, out);
}